// Round 5
// baseline (238.203 us; speedup 1.0000x reference)
//
#include <hip/hip_runtime.h>
#include <math.h>

#define PATCH 96
#define STRIDE 48
#define NH 21
#define NW 21
#define NP (NH * NW)              // 441 patches per (b,c)
#define BATCH 8
#define CHAN 4
#define NBC (BATCH * CHAN)        // 32
#define IMG_H 1056
#define IMG_W 1056
#define ROWF 1056                 // floats per image row
#define NHB 44                    // 24-row half-bands
#define NCHUNK 22                 // 48-col chunks
#define NSTAT 6                   // s1, s2, gxi, gxb, gyi, gyb
#define NPIX 9216.0f
#define NGRAD 9120.0f
#define SLAB (NHB * NCHUNK * NSTAT)   // 5808 floats per bc
#define RB 5                      // rows per staging batch (25 = 5 batches)

typedef __attribute__((address_space(3))) unsigned int lds_uint;
typedef __attribute__((address_space(1))) const unsigned int glb_uint;

// async global->LDS, 16B per lane; LDS dest = wave-uniform base + lane*16
__device__ __forceinline__ void stage16(const float* g, float* l) {
  __builtin_amdgcn_global_load_lds((glb_uint*)g, (lds_uint*)l, 16, 0, 0);
}

// ---------------------------------------------------------------------------
// Phase 1: one block per (bc, half-band), 320 threads (264 active own 4 cols).
// R0's register-staged loop was LATENCY-bound (~88 us, ~800 GB/s): per-CU
// in-flight bytes ~4.4 KB vs the ~9.2 KB needed to sustain HBM BW at ~900 cy
// latency, and in-flight depth is VGPR-bound (R4: VGPR=32 -> 103 us).
// Fix: global_load_lds staging — outstanding-load depth lives in the vmcnt
// queue, not VGPRs. Double-buffered 5-row batches; one row = 4224 B = exactly
// 264 lanes x 16 B. Sync = __syncthreads (compiler's vmcnt(0) drain at the
// barrier is the producer-consumer handshake; no fragile counted-vmcnt asm).
// In-flight per CU = 3 blocks x 5 rows x 4224 B ~ 63 KB >> 9.2 KB -> BW-bound.
// gy carries `prev` across batches in-register; row 24 contributes only gyb;
// hb=43 clamps row 24 -> row 23 so gyb = 0 naturally.
// ---------------------------------------------------------------------------
__global__ __launch_bounds__(320) void band_stats_kernel(
    const float* __restrict__ x, float* __restrict__ pf, int* __restrict__ cnt) {
  __shared__ float L[2][RB * ROWF];       // 42240 B
  __shared__ float acc[NCHUNK * NSTAT];   // 528 B

  const int t = threadIdx.x;              // 0..319
  const int bc = blockIdx.x / NHB;
  const int hb = blockIdx.x - bc * NHB;
  // zero the phase-2 ticket counter (poisoned workspace)
  if (blockIdx.x == 0 && t == 0) cnt[0] = 0;

  const bool active = t < 264;
  const int tc = active ? t : 263;        // clamp idle lanes to a safe column
  // neighbor offset in LDS row: +4 except image edge (noff=3 -> d4==0, lands
  // in the never-read gxb of chunk 21)
  const int noff = (tc == 263) ? 3 : 4;

  const float* base = x + (size_t)bc * (IMG_H * IMG_W);
  const int row0 = hb * 24;
  const int wbase = (t >> 6) << 8;        // wave-uniform LDS float base (256*w)

  // stage batch bt (5 rows) into buffer bufi; per-lane global addr, per-wave
  // uniform LDS base (+lane*16 added by HW). Inactive lanes masked by exec.
#define STAGE(bt, bufi)                                                   \
  do {                                                                    \
    if (active) {                                                         \
      _Pragma("unroll")                                                   \
      for (int rr = 0; rr < RB; ++rr) {                                   \
        int grow = row0 + (bt) * RB + rr;                                 \
        if (grow > IMG_H - 1) grow = IMG_H - 1;                           \
        stage16(base + (size_t)grow * ROWF + 4 * tc,                      \
                &L[bufi][rr * ROWF + wbase]);                             \
      }                                                                   \
    }                                                                     \
  } while (0)

  float s1 = 0.f, s2 = 0.f, gxi = 0.f, gxb = 0.f, gyi = 0.f, gyb = 0.f;
  const bool bnd_is_gxb = ((tc % 12) == 11);   // last quad of its chunk
  float4 prev{0.f, 0.f, 0.f, 0.f};             // ri==0 guard ensures unused

#define SUMS_GX(A, nxt)                                                  \
  do {                                                                   \
    s1 += (A).x + (A).y + (A).z + (A).w;                                 \
    s2 += (A).x * (A).x + (A).y * (A).y + (A).z * (A).z + (A).w * (A).w; \
    float d1 = (A).y - (A).x, d2 = (A).z - (A).y, d3 = (A).w - (A).z;    \
    float d4 = (nxt) - (A).w;                                            \
    gxi += d1 * d1 + d2 * d2 + d3 * d3;                                  \
    float bd = d4 * d4;                                                  \
    if (bnd_is_gxb) gxb += bd; else gxi += bd;                           \
  } while (0)

  STAGE(0, 0);
  __syncthreads();                        // batch 0 resident
#pragma unroll
  for (int bt = 0; bt < 5; ++bt) {
    if (bt < 4) STAGE(bt + 1, (bt + 1) & 1);   // prefetch next batch
    const float* Lb = &L[bt & 1][0];
#pragma unroll
    for (int rr = 0; rr < RB; ++rr) {
      const int ri = bt * RB + rr;        // compile-time after unroll
      const float4 A = *(const float4*)&Lb[rr * ROWF + 4 * tc];
      if (ri < 24) {                      // row 24 is only the gyb partner
        const float nxt = Lb[rr * ROWF + 4 * tc + noff];
        SUMS_GX(A, nxt);
      }
      if (ri > 0) {
        const float e0 = A.x - prev.x, e1 = A.y - prev.y,
                    e2 = A.z - prev.z, e3 = A.w - prev.w;
        const float sq = e0 * e0 + e1 * e1 + e2 * e2 + e3 * e3;
        if (ri < 24) gyi += sq; else gyb += sq;
      }
      prev = A;
    }
    __syncthreads();   // drains the prefetch (vmcnt0) + protects buffer reuse
  }
#undef SUMS_GX
#undef STAGE

  for (int i = t; i < NCHUNK * NSTAT; i += 320) acc[i] = 0.f;
  __syncthreads();
  if (active) {
    const int chunk = tc / 12;
    atomicAdd(&acc[chunk * NSTAT + 0], s1);
    atomicAdd(&acc[chunk * NSTAT + 1], s2);
    atomicAdd(&acc[chunk * NSTAT + 2], gxi);
    atomicAdd(&acc[chunk * NSTAT + 3], gxb);
    atomicAdd(&acc[chunk * NSTAT + 4], gyi);
    atomicAdd(&acc[chunk * NSTAT + 5], gyb);
  }
  __syncthreads();
  float* dst = pf + (size_t)(bc * NHB + hb) * (NCHUNK * NSTAT);
  for (int i = t; i < NCHUNK * NSTAT; i += 320) dst[i] = acc[i];
}

// ---------------------------------------------------------------------------
// Phase 2+3 merged: one block per bc (32 blocks). Proven in rounds 2-3.
// ---------------------------------------------------------------------------
__global__ __launch_bounds__(512) void patch_finalize_kernel(
    const float* __restrict__ pf, float* __restrict__ featsG,
    int* __restrict__ cnt, const float* __restrict__ mu0_full,
    const float* __restrict__ cov_full, float* __restrict__ out) {
  __shared__ float S[SLAB];                   // 23.2 KB
  __shared__ float wsum[8][3];
  __shared__ double inv_s[12][12];
  __shared__ float fin_s[96 + BATCH];
  __shared__ int ticket_s;

  const int bc = blockIdx.x;
  const int t = threadIdx.x;
  const float* src = pf + (size_t)bc * SLAB;
  for (int i = t; i < SLAB; i += 512) S[i] = src[i];
  __syncthreads();

  float fmu = 0.f, fvar = 0.f, fg = 0.f;
  if (t < NP) {
    const int ph = t / NW, pw = t - ph * NW;
    const int h0 = 2 * ph;
#define AT(h, c, s) S[((h) * NCHUNK + (c)) * NSTAT + (s)]
    float S1 = 0.f, S2 = 0.f, Gx = 0.f, Gy = 0.f;
#pragma unroll
    for (int hh = 0; hh < 4; ++hh) {
      const int h = h0 + hh;
      S1 += AT(h, pw, 0) + AT(h, pw + 1, 0);
      S2 += AT(h, pw, 1) + AT(h, pw + 1, 1);
      Gx += AT(h, pw, 2) + AT(h, pw, 3) + AT(h, pw + 1, 2);
      Gy += AT(h, pw, 4) + AT(h, pw + 1, 4);
    }
#pragma unroll
    for (int hh = 0; hh < 3; ++hh) {
      const int h = h0 + hh;
      Gy += AT(h, pw, 5) + AT(h, pw + 1, 5);
    }
#undef AT
    fmu = S1 / NPIX;
    fvar = (S2 - S1 * S1 / NPIX) / (NPIX - 1.f);
    fg = sqrtf((Gx + Gy) / NGRAD);
  }
#pragma unroll
  for (int off = 32; off > 0; off >>= 1) {
    fmu += __shfl_xor(fmu, off);
    fvar += __shfl_xor(fvar, off);
    fg += __shfl_xor(fg, off);
  }
  const int wave = t >> 6;
  if ((t & 63) == 0) { wsum[wave][0] = fmu; wsum[wave][1] = fvar; wsum[wave][2] = fg; }
  __syncthreads();
  if (t == 0) {
    float m = 0.f, v = 0.f, g = 0.f;
#pragma unroll
    for (int w = 0; w < 8; ++w) { m += wsum[w][0]; v += wsum[w][1]; g += wsum[w][2]; }
    const int b = bc / CHAN, c = bc - b * CHAN;
    featsG[b * 12 + 0 + c] = m / (float)NP;
    featsG[b * 12 + 4 + c] = v / (float)NP;
    featsG[b * 12 + 8 + c] = g / (float)NP;
    __threadfence();                      // release featsG (32 fences: cheap)
    ticket_s = atomicAdd(cnt, 1);         // device-scope ticket
  }
  __syncthreads();
  if (ticket_s != NBC - 1) return;

  // ---- last block: finalize ----
  __threadfence();                        // acquire
  if (t < 96)
    fin_s[t] = __hip_atomic_load(&featsG[t], __ATOMIC_RELAXED,
                                 __HIP_MEMORY_SCOPE_AGENT);
  __syncthreads();

  if (t < 64) {   // wave 0: register-resident Gauss-Jordan, lane c owns col c
    double M[12];
#pragma unroll
    for (int r = 0; r < 12; ++r) {
      double v = 0.0;
      if (t < 12) v = (double)cov_full[r * 36 + t];
      else if (t < 24) v = (t - 12 == r) ? 1.0 : 0.0;
      M[r] = v;
    }
#pragma unroll
    for (int k = 0; k < 12; ++k) {
      const double piv = __shfl(M[k], k);
      const double ip = 1.0 / piv;
      M[k] *= ip;
#pragma unroll
      for (int r = 0; r < 12; ++r) {
        if (r == k) continue;
        const double f = __shfl(M[r], k);   // old M[r][k], read before update
        M[r] -= f * M[k];
      }
    }
    if (t >= 12 && t < 24) {
      const int j = t - 12;
#pragma unroll
      for (int r = 0; r < 12; ++r) inv_s[r][j] = M[r];
    }
  }
  __syncthreads();

  if (t < BATCH) {
    double acc = 0.0;
    double d[12];
#pragma unroll
    for (int i = 0; i < 12; ++i)
      d[i] = (double)fin_s[t * 12 + i] - (double)mu0_full[i];
#pragma unroll
    for (int i = 0; i < 12; ++i) {
      double row = 0.0;
#pragma unroll
      for (int j = 0; j < 12; ++j) row += inv_s[i][j] * d[j];
      acc += d[i] * row;
    }
    fin_s[96 + t] = (float)sqrt(acc);
  }
  __syncthreads();
  if (t == 0) {
    float m = 0.f;
#pragma unroll
    for (int b = 0; b < BATCH; ++b) m += fin_s[96 + b];
    out[0] = m / (float)BATCH;
  }
}

extern "C" void kernel_launch(void* const* d_in, const int* in_sizes, int n_in,
                              void* d_out, int out_size, void* d_ws, size_t ws_size,
                              hipStream_t stream) {
  const float* x   = (const float*)d_in[0];
  const float* mu0 = (const float*)d_in[1];
  const float* cov = (const float*)d_in[2];
  float* out = (float*)d_out;
  float* pf     = (float*)d_ws;                         // 32*5808 floats = 743 KB
  float* featsG = pf + (size_t)NBC * SLAB;              // 96 floats
  int* cnt      = (int*)(featsG + 96);                  // 1 ticket counter

  band_stats_kernel<<<NBC * NHB, 320, 0, stream>>>(x, pf, cnt);
  patch_finalize_kernel<<<NBC, 512, 0, stream>>>(pf, featsG, cnt, mu0, cov, out);
}